// Round 1
// baseline (554.675 us; speedup 1.0000x reference)
//
#include <hip/hip_runtime.h>

// VQ: B=8, C_IN=1024, T=8192, K=1024, D=8
#define B_   8
#define C_   1024
#define T_   8192
#define K_   1024
#define D_   8
#define CT_  (C_ * T_)            // 8388608
#define BT_  (B_ * T_)            // 65536
#define OUTN_ ((size_t)B_ * CT_)  // 67108864 (output 0 elements)

// ---------------------------------------------------------------------------
// Kernel 1: fused in-proj + nearest-codebook search.
// Block = 256 threads = 4 waves, handles 64 consecutive (b,t) positions.
//   phase A: waves split C=1024 into 4 chunks of 256; each thread accumulates
//            the 8-dim partial projection for its t.  z reads are coalesced
//            (lane = t), in_w is staged transposed in LDS (wave-uniform
//            broadcast b128 reads).
//   reduce : LDS sum of the 4 partials per (t,d).
//   phase B: waves split K=1024 into 4 chunks of 256; score
//            0.5||w||^2 - in_b.w - enc.w  (bias folded into the norm table).
//            Codebook rows are wave-uniform -> scalar loads from global.
//   final  : cross-wave min (ties -> smallest k, matching np.argmax-first).
// ---------------------------------------------------------------------------
__global__ __launch_bounds__(256) void vq_encode_kernel(
    const float* __restrict__ z, const float* __restrict__ in_w,
    const float* __restrict__ in_b, const float* __restrict__ cb,
    float* __restrict__ ids_f)
{
    __shared__ float s_inwT[C_ * D_];     // 32 KB, [c][d]
    __shared__ float s_nrm[K_];           // 4 KB, 0.5||w_k||^2 - in_b.w_k
    __shared__ float s_encp[4][D_][64];   // 8 KB, partial enc [wave][d][t]
    __shared__ float s_val[4][64];        // 1 KB
    __shared__ int   s_idx[4][64];        // 1 KB

    const int tid = threadIdx.x;
    const int w   = tid >> 6;
    const int l   = tid & 63;
    const int bt0 = blockIdx.x * 64;
    const int b   = bt0 >> 13;            // T = 8192
    const int t0  = bt0 & (T_ - 1);

    // --- stage in_w transposed: in_w is [D][C] row-major -> s_inwT[c*8+d]
    for (int i = tid; i < C_ * D_; i += 256) {
        const int d = i >> 10;
        const int c = i & (C_ - 1);
        s_inwT[c * D_ + d] = in_w[i];
    }
    // --- norm table with in_b folded in (enc bias never needs to be added)
    {
        float ib[D_];
#pragma unroll
        for (int d = 0; d < D_; ++d) ib[d] = in_b[d];
#pragma unroll
        for (int j = 0; j < 4; ++j) {
            const int k = tid + j * 256;
            const float4* cp = (const float4*)(cb + k * D_);
            const float4 a = cp[0], q = cp[1];
            const float ss = a.x*a.x + a.y*a.y + a.z*a.z + a.w*a.w
                           + q.x*q.x + q.y*q.y + q.z*q.z + q.w*q.w;
            const float qq = ib[0]*a.x + ib[1]*a.y + ib[2]*a.z + ib[3]*a.w
                           + ib[4]*q.x + ib[5]*q.y + ib[6]*q.z + ib[7]*q.w;
            s_nrm[k] = 0.5f * ss - qq;
        }
    }
    __syncthreads();

    // --- phase A: partial projection over this wave's c-chunk
    float acc[D_];
#pragma unroll
    for (int d = 0; d < D_; ++d) acc[d] = 0.0f;
    const float* zp = z + (size_t)b * CT_ + (size_t)(w * 256) * T_ + (t0 + l);
#pragma unroll 8
    for (int i = 0; i < 256; ++i) {
        const float zv = zp[(size_t)i * T_];
        const float4* wp = (const float4*)&s_inwT[(w * 256 + i) * D_];
        const float4 w0 = wp[0], w1 = wp[1];
        acc[0] = fmaf(zv, w0.x, acc[0]);
        acc[1] = fmaf(zv, w0.y, acc[1]);
        acc[2] = fmaf(zv, w0.z, acc[2]);
        acc[3] = fmaf(zv, w0.w, acc[3]);
        acc[4] = fmaf(zv, w1.x, acc[4]);
        acc[5] = fmaf(zv, w1.y, acc[5]);
        acc[6] = fmaf(zv, w1.z, acc[6]);
        acc[7] = fmaf(zv, w1.w, acc[7]);
    }
#pragma unroll
    for (int d = 0; d < D_; ++d) s_encp[w][d][l] = acc[d];
    __syncthreads();

    // --- reduce the 4 partials: 512 (d,t) pairs, 2 per thread, no overlap
    for (int p = tid; p < 512; p += 256) {
        const int d = p >> 6, tt = p & 63;
        s_encp[0][d][tt] = s_encp[0][d][tt] + s_encp[1][d][tt]
                         + s_encp[2][d][tt] + s_encp[3][d][tt];
    }
    __syncthreads();

    float e[D_];
#pragma unroll
    for (int d = 0; d < D_; ++d) e[d] = s_encp[0][d][l];

    // --- phase B: argmin over this wave's k-chunk
    const int wu = __builtin_amdgcn_readfirstlane(w);  // force scalar k-base
    float best = 3.4e38f;
    int   bi   = 0;
    for (int j = 0; j < 256; ++j) {
        const int k = wu * 256 + j;
        const float4* cp = (const float4*)(cb + k * D_);  // uniform -> s_load
        const float4 a = cp[0], q = cp[1];
        float s = s_nrm[k];
        s = fmaf(-e[0], a.x, s);
        s = fmaf(-e[1], a.y, s);
        s = fmaf(-e[2], a.z, s);
        s = fmaf(-e[3], a.w, s);
        s = fmaf(-e[4], q.x, s);
        s = fmaf(-e[5], q.y, s);
        s = fmaf(-e[6], q.z, s);
        s = fmaf(-e[7], q.w, s);
        if (s < best) { best = s; bi = k; }   // strict < : first min wins ties
    }
    s_val[w][l] = best;
    s_idx[w][l] = bi;
    __syncthreads();

    if (tid < 64) {
        float bv = s_val[0][l];
        int   bb = s_idx[0][l];
#pragma unroll
        for (int ww = 1; ww < 4; ++ww) {
            const float v = s_val[ww][l];
            if (v < bv) { bv = v; bb = s_idx[ww][l]; }
        }
        ids_f[bt0 + l] = (float)bb;           // ids output as float32
    }
}

// ---------------------------------------------------------------------------
// Kernel 2: decode (embedding gather + 1x1 out-proj).
// Block = 256 threads: 1024 consecutive t (4/thread, float4 stores) x 128 c.
// Codebook staged TRANSPOSED in LDS ([d][k]) so random-id gathers are
// spread across banks.  out_w rows / out_b are block-uniform -> scalar loads.
// ---------------------------------------------------------------------------
__global__ __launch_bounds__(256) void vq_decode_kernel(
    const float* __restrict__ ids_f, const float* __restrict__ cb,
    const float* __restrict__ out_w, const float* __restrict__ out_b,
    float* __restrict__ out)
{
    __shared__ float s_cbT[D_ * K_];   // 32 KB, [d][k]

    const int tid = threadIdx.x;
    for (int i = tid; i < K_ * D_ / 4; i += 256) {   // 2048 float4, 8/thread
        const float4 v = ((const float4*)cb)[i];
        const int k = i >> 1;
        const int d0 = (i & 1) * 4;
        s_cbT[(d0 + 0) * K_ + k] = v.x;
        s_cbT[(d0 + 1) * K_ + k] = v.y;
        s_cbT[(d0 + 2) * K_ + k] = v.z;
        s_cbT[(d0 + 3) * K_ + k] = v.w;
    }
    __syncthreads();

    const int blk = blockIdx.x;
    const int bt0 = (blk >> 3) * 1024;        // 64 t-tiles of 1024
    const int c0  = (blk & 7) * 128;          // 8 c-tiles of 128
    const int b   = bt0 >> 13;
    const int tt  = (bt0 & (T_ - 1)) + tid * 4;

    const float4 idv = *(const float4*)(ids_f + bt0 + tid * 4);
    const int k0 = (int)idv.x, k1 = (int)idv.y, k2 = (int)idv.z, k3 = (int)idv.w;

    float r0[D_], r1[D_], r2[D_], r3[D_];
#pragma unroll
    for (int d = 0; d < D_; ++d) {
        r0[d] = s_cbT[d * K_ + k0];
        r1[d] = s_cbT[d * K_ + k1];
        r2[d] = s_cbT[d * K_ + k2];
        r3[d] = s_cbT[d * K_ + k3];
    }

    float* op = out + (size_t)b * CT_ + (size_t)c0 * T_ + tt;
#pragma unroll 4
    for (int j = 0; j < 128; ++j) {
        const int c = c0 + j;
        const float4* wp = (const float4*)(out_w + c * D_);  // uniform
        const float4 w0 = wp[0], w1 = wp[1];
        const float bias = out_b[c];
        float wr[D_];
        wr[0] = w0.x; wr[1] = w0.y; wr[2] = w0.z; wr[3] = w0.w;
        wr[4] = w1.x; wr[5] = w1.y; wr[6] = w1.z; wr[7] = w1.w;
        float4 o;
        o.x = bias; o.y = bias; o.z = bias; o.w = bias;
#pragma unroll
        for (int d = 0; d < D_; ++d) {
            o.x = fmaf(r0[d], wr[d], o.x);
            o.y = fmaf(r1[d], wr[d], o.y);
            o.z = fmaf(r2[d], wr[d], o.z);
            o.w = fmaf(r3[d], wr[d], o.w);
        }
        *(float4*)(op + (size_t)j * T_) = o;
    }
}

extern "C" void kernel_launch(void* const* d_in, const int* in_sizes, int n_in,
                              void* d_out, int out_size, void* d_ws, size_t ws_size,
                              hipStream_t stream) {
    const float* z    = (const float*)d_in[0];
    const float* in_w = (const float*)d_in[1];
    const float* in_b = (const float*)d_in[2];
    const float* cb   = (const float*)d_in[3];
    const float* ow   = (const float*)d_in[4];
    const float* ob   = (const float*)d_in[5];

    float* out   = (float*)d_out;
    float* ids_f = out + OUTN_;   // output 1 (ids as float) follows output 0

    vq_encode_kernel<<<BT_ / 64, 256, 0, stream>>>(z, in_w, in_b, cb, ids_f);
    vq_decode_kernel<<<(BT_ / 1024) * 8, 256, 0, stream>>>(ids_f, cb, ow, ob, out);
}

// Round 2
// 523.817 us; speedup vs baseline: 1.0589x; 1.0589x over previous
//
#include <hip/hip_runtime.h>

// VQ: B=8, C_IN=1024, T=8192, K=1024, D=8
#define B_   8
#define C_   1024
#define T_   8192
#define K_   1024
#define D_   8
#define CT_  (C_ * T_)            // 8388608
#define BT_  (B_ * T_)            // 65536
#define OUTN_ ((size_t)B_ * CT_)  // 67108864 (output 0 elements)

// ---------------------------------------------------------------------------
// Prologue: wT[c][d] = in_w[d][c]  (contiguous 32 B rows -> s_load_dwordx8)
//           nrm[k]   = 0.5*||cb_k||^2 - in_b . cb_k   (bias folded in)
// ---------------------------------------------------------------------------
__global__ __launch_bounds__(256) void vq_prep(
    const float* __restrict__ in_w, const float* __restrict__ in_b,
    const float* __restrict__ cb, float* __restrict__ wT,
    float* __restrict__ nrm)
{
    const int i = blockIdx.x * 256 + threadIdx.x;
    if (i < C_ * D_) {
        const int d = i >> 10;
        const int c = i & (C_ - 1);
        wT[c * D_ + d] = in_w[i];
    }
    if (i < K_) {
        float s = 0.0f, q = 0.0f;
#pragma unroll
        for (int d = 0; d < D_; ++d) {
            const float w = cb[i * D_ + d];
            s = fmaf(w, w, s);
            q = fmaf(in_b[d], w, q);
        }
        nrm[i] = 0.5f * s - q;
    }
}

// ---------------------------------------------------------------------------
// Fused encode + argmin + decode.  Block = 256 thr = 4 waves, 64 t's.
// LDS: one 2048-float arena (8 KB) reused across phases:
//   phase A partials: [w][d][t]  (4 planes of 512 floats)
//   phase B results : val @ [1024..1279], idx @ [1280..1535]
//   decode          : zq rows @ [0..511]  ([t][d])
// All weight/codebook/bias accesses are wave-uniform -> scalar loads.
// ---------------------------------------------------------------------------
__global__ __launch_bounds__(256, 4) void vq_fused(
    const float* __restrict__ z, const float* __restrict__ wT,
    const float* __restrict__ nrm, const float* __restrict__ cb,
    const float* __restrict__ out_w, const float* __restrict__ out_b,
    float* __restrict__ out, float* __restrict__ ids_f)
{
    __shared__ float s_p[2048];   // 8 KB

    const int tid = threadIdx.x;
    const int wu  = __builtin_amdgcn_readfirstlane(tid >> 6);  // provably uniform
    const int l   = tid & 63;
    const int bt0 = blockIdx.x * 64;
    const int b   = bt0 >> 13;                 // T = 8192
    const int t0  = bt0 & (T_ - 1);
    const int c0  = wu * 256;                  // this wave's c / k chunk base

    // ---- phase A: partial projection, wave's 256-c chunk, 16-deep loads ----
    float acc[D_];
#pragma unroll
    for (int d = 0; d < D_; ++d) acc[d] = 0.0f;

    const float* zp = z + (size_t)b * CT_ + (size_t)c0 * T_ + (t0 + l);
    for (int i0 = 0; i0 < 256; i0 += 16) {
        float zv[16];
#pragma unroll
        for (int u = 0; u < 16; ++u) zv[u] = zp[(size_t)(i0 + u) * T_];
#pragma unroll
        for (int u = 0; u < 16; ++u) {
            const float* wr = wT + (size_t)(c0 + i0 + u) * D_;  // uniform -> s_load
#pragma unroll
            for (int d = 0; d < D_; ++d) acc[d] = fmaf(zv[u], wr[d], acc[d]);
        }
    }
#pragma unroll
    for (int d = 0; d < D_; ++d) s_p[wu * 512 + d * 64 + l] = acc[d];
    __syncthreads();

    // ---- reduce 4 wave-partials into plane 0 ----
    for (int p = tid; p < 512; p += 256)
        s_p[p] = s_p[p] + s_p[512 + p] + s_p[1024 + p] + s_p[1536 + p];
    __syncthreads();

    float e[D_];
#pragma unroll
    for (int d = 0; d < D_; ++d) e[d] = s_p[d * 64 + l];

    // ---- phase B: argmin over wave's 256-k chunk (uniform scalar loads) ----
    float best = 3.4e38f;
    int   bi   = 0;
    for (int j = 0; j < 256; ++j) {
        const int k = c0 + j;
        const float* cr = cb + (size_t)k * D_;   // uniform -> s_load_dwordx8
        float s = nrm[k];                         // uniform -> s_load
#pragma unroll
        for (int d = 0; d < D_; ++d) s = fmaf(-e[d], cr[d], s);
        if (s < best) { best = s; bi = k; }       // strict < : smallest k wins
    }
    s_p[1024 + wu * 64 + l] = best;
    ((int*)s_p)[1280 + wu * 64 + l] = bi;
    __syncthreads();

    // ---- final cross-wave min; write ids; stage winning codebook rows ----
    if (tid < 64) {
        float bv = s_p[1024 + l];
        int   bb = ((int*)s_p)[1280 + l];
#pragma unroll
        for (int ww = 1; ww < 4; ++ww) {
            const float v = s_p[1024 + ww * 64 + l];
            if (v < bv) { bv = v; bb = ((int*)s_p)[1280 + ww * 64 + l]; }
        }
        ids_f[bt0 + l] = (float)bb;
        const float4* cp = (const float4*)(cb + (size_t)bb * D_);
        const float4 a = cp[0], q = cp[1];
        float* zq = s_p + l * D_;                 // plane 0 reuse: [t][d]
        zq[0] = a.x; zq[1] = a.y; zq[2] = a.z; zq[3] = a.w;
        zq[4] = q.x; zq[5] = q.y; zq[6] = q.z; zq[7] = q.w;
    }
    __syncthreads();

    // ---- decode: wave writes its 256-c chunk for all 64 t ----
    float r[D_];
#pragma unroll
    for (int d = 0; d < D_; ++d) r[d] = s_p[l * D_ + d];

    float* op = out + (size_t)b * CT_ + (size_t)c0 * T_ + (t0 + l);
#pragma unroll 8
    for (int j = 0; j < 256; ++j) {
        const int c = c0 + j;
        const float* wr = out_w + (size_t)c * D_;  // uniform -> s_load_dwordx8
        float o = out_b[c];                         // uniform -> s_load
#pragma unroll
        for (int d = 0; d < D_; ++d) o = fmaf(r[d], wr[d], o);
        op[(size_t)j * T_] = o;                     // 256 B / wave-instr
    }
}

extern "C" void kernel_launch(void* const* d_in, const int* in_sizes, int n_in,
                              void* d_out, int out_size, void* d_ws, size_t ws_size,
                              hipStream_t stream) {
    const float* z    = (const float*)d_in[0];
    const float* in_w = (const float*)d_in[1];
    const float* in_b = (const float*)d_in[2];
    const float* cb   = (const float*)d_in[3];
    const float* ow   = (const float*)d_in[4];
    const float* ob   = (const float*)d_in[5];

    float* out   = (float*)d_out;
    float* ids_f = out + OUTN_;      // output 1 (ids as float) follows output 0

    float* wT  = (float*)d_ws;       // 8192 floats
    float* nrm = wT + C_ * D_;       // 1024 floats (36 KB total scratch)

    vq_prep<<<32, 256, 0, stream>>>(in_w, in_b, cb, wT, nrm);
    vq_fused<<<BT_ / 64, 256, 0, stream>>>(z, wT, nrm, cb, ow, ob, out, ids_f);
}

// Round 3
// 468.590 us; speedup vs baseline: 1.1837x; 1.1179x over previous
//
#include <hip/hip_runtime.h>

// VQ: B=8, C_IN=1024, T=8192, K=1024, D=8
#define B_   8
#define C_   1024
#define T_   8192
#define K_   1024
#define D_   8
#define CT_  (C_ * T_)            // 8388608
#define BT_  (B_ * T_)            // 65536
#define OUTN_ ((size_t)B_ * CT_)  // 67108864 (output 0 elements)

// ---------------------------------------------------------------------------
// Prologue: wT[c][d] = in_w[d][c]  (contiguous 32 B rows -> s_load)
//           nrm[k]   = 0.5*||cb_k||^2 - in_b . cb_k   (bias folded in)
// ---------------------------------------------------------------------------
__global__ __launch_bounds__(256) void vq_prep(
    const float* __restrict__ in_w, const float* __restrict__ in_b,
    const float* __restrict__ cb, float* __restrict__ wT,
    float* __restrict__ nrm)
{
    const int i = blockIdx.x * 256 + threadIdx.x;
    if (i < C_ * D_) {
        const int d = i >> 10;
        const int c = i & (C_ - 1);
        wT[c * D_ + d] = in_w[i];
    }
    if (i < K_) {
        float s = 0.0f, q = 0.0f;
#pragma unroll
        for (int d = 0; d < D_; ++d) {
            const float w = cb[i * D_ + d];
            s = fmaf(w, w, s);
            q = fmaf(in_b[d], w, q);
        }
        nrm[i] = 0.5f * s - q;
    }
}

// ---------------------------------------------------------------------------
// Fused encode + argmin + decode.  Grid = 256 blocks (1/CU), 1024 thr = 16
// waves.  Block owns a 256-t tile; wave w owns the 64-c chunk [64w, 64w+64).
// Each lane holds 4 consecutive t's -> ALL global z/out traffic is float4
// (1 KB per wave-instruction, DRAM-friendly).  Weights / codebook / norms are
// wave-uniform -> scalar loads.
// LDS arena: s_part[32][1025] for the 16-way cross-wave partial reduce
// (stride 1025 == 1 mod 32 -> conflict-free), reused for argmin val/idx.
// ---------------------------------------------------------------------------
__global__ __launch_bounds__(1024, 4) void vq_fused(
    const float* __restrict__ z, const float* __restrict__ wT,
    const float* __restrict__ nrm, const float* __restrict__ cb,
    const float* __restrict__ out_w, const float* __restrict__ out_b,
    float* __restrict__ out, float* __restrict__ ids_f)
{
    __shared__ float s_part[32 * 1025];   // 131.2 KB
    __shared__ float s_enc[2048];         // 8 KB   enc[k=tt*8+d][lane]
    __shared__ float s_zq[256 * 9];       // 9.2 KB zq rows, stride-9 pad

    float* s_val = s_part;                // [16][256]  (reuse, dead planes)
    int*   s_idx = (int*)(s_part + 4096); // [16][256]

    const int tid = threadIdx.x;
    const int wu  = __builtin_amdgcn_readfirstlane(tid >> 6); // uniform wave id
    const int l   = tid & 63;
    const int blk = blockIdx.x;
    const int b   = blk >> 5;                 // 32 t-tiles per b
    const int t0  = (blk & 31) << 8;          // 256-t tile base
    const int c0  = wu << 6;                  // wave's c / k chunk base

    // ---- phase A: partial projection over wave's 64-c chunk, float4 t's ----
    float acc[4][D_];
#pragma unroll
    for (int tt = 0; tt < 4; ++tt)
#pragma unroll
        for (int d = 0; d < D_; ++d) acc[tt][d] = 0.0f;

    const float4* zp =
        (const float4*)(z + (size_t)b * CT_ + (size_t)c0 * T_ + t0) + l;
    for (int i = 0; i < 64; i += 4) {
        float4 zv[4];
#pragma unroll
        for (int u = 0; u < 4; ++u)
            zv[u] = zp[(size_t)(i + u) * (T_ / 4)];
#pragma unroll
        for (int u = 0; u < 4; ++u) {
            const float* wr = wT + (size_t)(c0 + i + u) * D_;  // uniform
#pragma unroll
            for (int d = 0; d < D_; ++d) {
                const float wv = wr[d];
                acc[0][d] = fmaf(zv[u].x, wv, acc[0][d]);
                acc[1][d] = fmaf(zv[u].y, wv, acc[1][d]);
                acc[2][d] = fmaf(zv[u].z, wv, acc[2][d]);
                acc[3][d] = fmaf(zv[u].w, wv, acc[3][d]);
            }
        }
    }
    // stage partials: row k = tt*8+d, col = tid  (bank = (k+tid)%32, CF)
#pragma unroll
    for (int tt = 0; tt < 4; ++tt)
#pragma unroll
        for (int d = 0; d < D_; ++d)
            s_part[(tt * D_ + d) * 1025 + tid] = acc[tt][d];
    __syncthreads();

    // ---- reduce 16 wave-partials -> s_enc[k*64 + lane] ----
#pragma unroll
    for (int r = 0; r < 2; ++r) {
        const int p = tid + r * 1024;
        const int k = p >> 6, l2 = p & 63;
        float s = 0.0f;
#pragma unroll
        for (int ww = 0; ww < 16; ++ww)
            s += s_part[k * 1025 + ww * 64 + l2];
        s_enc[p] = s;
    }
    __syncthreads();

    // ---- phase B: argmin over wave's 64-k chunk for lane's 4 t's ----
    float e[4][D_];
#pragma unroll
    for (int tt = 0; tt < 4; ++tt)
#pragma unroll
        for (int d = 0; d < D_; ++d)
            e[tt][d] = s_enc[(tt * D_ + d) * 64 + l];

    float best[4];
    int   bi[4];
#pragma unroll
    for (int tt = 0; tt < 4; ++tt) { best[tt] = 3.4e38f; bi[tt] = 0; }

    for (int j = 0; j < 64; ++j) {
        const int k = c0 + j;
        const float* cr = cb + (size_t)k * D_;   // uniform -> s_load
        const float nk = nrm[k];                 // uniform -> s_load
#pragma unroll
        for (int tt = 0; tt < 4; ++tt) {
            float s = nk;
#pragma unroll
            for (int d = 0; d < D_; ++d) s = fmaf(-e[tt][d], cr[d], s);
            if (s < best[tt]) { best[tt] = s; bi[tt] = k; }  // first min wins
        }
    }
#pragma unroll
    for (int tt = 0; tt < 4; ++tt) {
        s_val[wu * 256 + 4 * l + tt] = best[tt];
        s_idx[wu * 256 + 4 * l + tt] = bi[tt];
    }
    __syncthreads();

    // ---- cross-wave argmin scan (w ascending == k ascending); zq gather ----
    if (tid < 256) {
        float bv = s_val[tid];
        int   bb = s_idx[tid];
#pragma unroll
        for (int ww = 1; ww < 16; ++ww) {
            const float v = s_val[ww * 256 + tid];
            if (v < bv) { bv = v; bb = s_idx[ww * 256 + tid]; }
        }
        ids_f[blk * 256 + tid] = (float)bb;
        const float4* cp = (const float4*)(cb + (size_t)bb * D_);
        const float4 a = cp[0], q = cp[1];
        float* zr = s_zq + tid * 9;
        zr[0] = a.x; zr[1] = a.y; zr[2] = a.z; zr[3] = a.w;
        zr[4] = q.x; zr[5] = q.y; zr[6] = q.z; zr[7] = q.w;
    }
    __syncthreads();

    // ---- decode: wave writes its 64-c chunk, float4 stores (1 KB/instr) ----
    float r4[4][D_];
#pragma unroll
    for (int tt = 0; tt < 4; ++tt)
#pragma unroll
        for (int d = 0; d < D_; ++d)
            r4[tt][d] = s_zq[(4 * l + tt) * 9 + d];

    float4* op = (float4*)(out + (size_t)b * CT_ + (size_t)c0 * T_ + t0) + l;
#pragma unroll 4
    for (int j = 0; j < 64; ++j) {
        const int c = c0 + j;
        const float* wr = out_w + (size_t)c * D_;  // uniform -> s_load
        const float bias = out_b[c];               // uniform -> s_load
        float4 o;
        o.x = bias; o.y = bias; o.z = bias; o.w = bias;
#pragma unroll
        for (int d = 0; d < D_; ++d) {
            const float wv = wr[d];
            o.x = fmaf(r4[0][d], wv, o.x);
            o.y = fmaf(r4[1][d], wv, o.y);
            o.z = fmaf(r4[2][d], wv, o.z);
            o.w = fmaf(r4[3][d], wv, o.w);
        }
        op[(size_t)j * (T_ / 4)] = o;
    }
}

extern "C" void kernel_launch(void* const* d_in, const int* in_sizes, int n_in,
                              void* d_out, int out_size, void* d_ws, size_t ws_size,
                              hipStream_t stream) {
    const float* z    = (const float*)d_in[0];
    const float* in_w = (const float*)d_in[1];
    const float* in_b = (const float*)d_in[2];
    const float* cb   = (const float*)d_in[3];
    const float* ow   = (const float*)d_in[4];
    const float* ob   = (const float*)d_in[5];

    float* out   = (float*)d_out;
    float* ids_f = out + OUTN_;      // output 1 (ids as float) follows output 0

    float* wT  = (float*)d_ws;       // 8192 floats
    float* nrm = wT + C_ * D_;       // 1024 floats

    vq_prep<<<32, 256, 0, stream>>>(in_w, in_b, cb, wT, nrm);
    vq_fused<<<256, 1024, 0, stream>>>(z, wT, nrm, cb, ow, ob, out, ids_f);
}